// Round 1
// baseline (1847.508 us; speedup 1.0000x reference)
//
#include <hip/hip_runtime.h>
#include <hip/hip_bf16.h>

#define NS 48
#define NV 10
#define NATT 78
#define HID 128
#define W1N 2304
#define W2N 480
#define W3N 100
#define W4N 480
#define WTOT 3364
#define CPAD 3376        // 211 * 16
#define NT 211           // column tiles of 16
#define NEDGE 50000
#define NNODE 10000
#define EPAD 50048       // 782 * 64
#define EPSV 1e-5f
#define INV_SQRT3 0.57735026918962576f
#define NORM0 0.13130643285972254f   // 1/sqrt(58)
#define NORM1 0.13130643285972254f

using short8 = __attribute__((ext_vector_type(8))) short;
using f32x4  = __attribute__((ext_vector_type(4))) float;

__device__ __forceinline__ unsigned short f2bf(float x) {
  union { float f; unsigned u; } v; v.f = x;
  unsigned r = v.u + 0x7fff + ((v.u >> 16) & 1);
  return (unsigned short)(r >> 16);
}

// ---------------- K0: fc_w2 (128 x 3364) -> Bt bf16 [CPAD][128] (transposed) ----
__global__ __launch_bounds__(256) void k_prep_bt(const float* __restrict__ w2,
                                                 unsigned short* __restrict__ Bt) {
  int idx = blockIdx.x * 256 + threadIdx.x;   // CPAD*128 total
  int c = idx >> 7, k = idx & 127;
  float val = (c < WTOT) ? w2[(size_t)k * WTOT + c] : 0.f;
  Bt[idx] = f2bf(val);
}

// ---------------- K1: h = relu(edge_attr @ fc_w1 + b1) -> bf16 [EPAD][128] ------
__global__ __launch_bounds__(256) void k_fc1(const float* __restrict__ ea,
                                             const float* __restrict__ w1,
                                             const float* __restrict__ b1,
                                             unsigned short* __restrict__ hbf) {
  __shared__ float sT[128][36];   // [k][edge_local], pad 36 keeps float4 align
  int tid = threadIdx.x;
  int e0 = blockIdx.x * 32;
  for (int i = tid; i < 32 * 128; i += 256) {
    int el = i >> 7, k = i & 127;
    int e = e0 + el;
    sT[k][el] = (e < NEDGE) ? ea[(size_t)e * 128 + k] : 0.f;
  }
  __syncthreads();
  int cg = tid & 31;   // 32 col groups * 4 cols
  int eg = tid >> 5;   // 8 edge groups * 4 edges
  float acc[4][4] = {};
  #pragma unroll 4
  for (int k = 0; k < 128; ++k) {
    float4 a = *(const float4*)&sT[k][eg * 4];
    float4 w = *(const float4*)&w1[k * 128 + cg * 4];
    float av[4] = {a.x, a.y, a.z, a.w};
    float wv[4] = {w.x, w.y, w.z, w.w};
    #pragma unroll
    for (int ii = 0; ii < 4; ++ii)
      #pragma unroll
      for (int jj = 0; jj < 4; ++jj)
        acc[ii][jj] += av[ii] * wv[jj];
  }
  float bb[4];
  #pragma unroll
  for (int jj = 0; jj < 4; ++jj) bb[jj] = b1[cg * 4 + jj];
  #pragma unroll
  for (int ii = 0; ii < 4; ++ii) {
    int e = e0 + eg * 4 + ii;
    bool val = e < NEDGE;
    unsigned short h4[4];
    #pragma unroll
    for (int jj = 0; jj < 4; ++jj) {
      float r = val ? fmaxf(acc[ii][jj] + bb[jj], 0.f) : 0.f;
      h4[jj] = f2bf(r);
    }
    uint2 pk;
    pk.x = (unsigned)h4[0] | ((unsigned)h4[1] << 16);
    pk.y = (unsigned)h4[2] | ((unsigned)h4[3] << 16);
    *(uint2*)(hbf + (size_t)e * 128 + cg * 4) = pk;
  }
}

// ---------------- K3: fused  w = h@fc_w2+b2  -> tensor product -> segment sum ---
__global__ __launch_bounds__(128) void k_tp(const unsigned short* __restrict__ hbf,
                                            const unsigned short* __restrict__ Bt,
                                            const float* __restrict__ b2,
                                            const int* __restrict__ eidx,
                                            const float* __restrict__ node_attr,
                                            const float* __restrict__ esh,
                                            float* __restrict__ summed,
                                            float* __restrict__ cnt) {
  __shared__ float outAcc[64][81];
  __shared__ float sF[64][NS];
  __shared__ float vF[64][30];
  __shared__ float dotN[64][NV];     // dot * INV_SQRT3 * NORM0
  __shared__ float p0F[64], q0F[64]; // sh0*NORM0, sh0*NORM1
  __shared__ float sh1nF[64][3];     // sh1 * NORM1
  __shared__ int   srcL[64];

  int tid = threadIdx.x;
  int e0 = blockIdx.x * 64;

  for (int i = tid; i < 64 * 81; i += 128) ((float*)outAcc)[i] = 0.f;

  if (tid < 64) {
    int el = tid, eg = e0 + el;
    bool val = eg < NEDGE;
    srcL[el] = val ? eidx[eg] : -1;
    int dst = val ? eidx[NEDGE + eg] : 0;
    const float* na = node_attr + (size_t)dst * NATT;
    float sh0 = 0.f, s1x = 0.f, s1y = 0.f, s1z = 0.f;
    if (val) {
      sh0 = esh[(size_t)eg * 4 + 0];
      s1x = esh[(size_t)eg * 4 + 1];
      s1y = esh[(size_t)eg * 4 + 2];
      s1z = esh[(size_t)eg * 4 + 3];
    }
    for (int u = 0; u < NS; ++u) sF[el][u] = val ? na[u] : 0.f;
    for (int u = 0; u < NV; ++u) {
      float v0 = 0.f, v1 = 0.f, v2 = 0.f;
      if (val) { v0 = na[NS + u*3]; v1 = na[NS + u*3 + 1]; v2 = na[NS + u*3 + 2]; }
      vF[el][u*3+0] = v0; vF[el][u*3+1] = v1; vF[el][u*3+2] = v2;
      dotN[el][u] = (v0*s1x + v1*s1y + v2*s1z) * (INV_SQRT3 * NORM0);
    }
    p0F[el] = sh0 * NORM0;
    q0F[el] = sh0 * NORM1;
    sh1nF[el][0] = s1x * NORM1; sh1nF[el][1] = s1y * NORM1; sh1nF[el][2] = s1z * NORM1;
  }
  __syncthreads();

  int lane = tid & 63;
  int wave = tid >> 6;   // 0..1, each wave owns 32 edges
  int quad = lane >> 4;
  int col  = lane & 15;

  // A fragments in registers: 32 edges x K=128, lane supplies A[m=lane&15][k=quad*8+j]
  short8 aF[2][4];
  {
    const short8* hp = (const short8*)hbf;
    #pragma unroll
    for (int mt = 0; mt < 2; ++mt) {
      size_t row = (size_t)(e0 + wave*32 + mt*16 + col) * 16;  // 16 short8 per row
      #pragma unroll
      for (int ks = 0; ks < 4; ++ks) aF[mt][ks] = hp[row + ks*4 + quad];
    }
  }

  const short8* bp8 = (const short8*)Bt;

  for (int t = 0; t < NT; ++t) {
    int c = t * 16 + col;
    short8 bF[4];
    size_t brow = (size_t)c * 16;
    #pragma unroll
    for (int ks = 0; ks < 4; ++ks) bF[ks] = bp8[brow + ks*4 + quad];

    float b2c = (c < WTOT) ? b2[c] : 0.f;
    int kind, uu = 0, vv = 0;
    if (c < W1N)                  { kind = 0; uu = c / NS;  vv = c % NS; }
    else if (c < W1N + W2N)       { int tt = c - W1N;             kind = 1; uu = tt / NV; vv = tt % NV; }
    else if (c < W1N + W2N + W3N) { int tt = c - (W1N + W2N);     kind = 2; uu = tt / NV; vv = tt % NV; }
    else if (c < WTOT)            { int tt = c - (W1N + W2N + W3N); kind = 3; uu = tt / NS; vv = tt % NS; }
    else kind = 4;

    #pragma unroll
    for (int mt = 0; mt < 2; ++mt) {
      f32x4 acc = {0.f, 0.f, 0.f, 0.f};
      #pragma unroll
      for (int ks = 0; ks < 4; ++ks)
        acc = __builtin_amdgcn_mfma_f32_16x16x32_bf16(aF[mt][ks], bF[ks], acc, 0, 0, 0);
      if (kind == 4) continue;
      int ebase = wave*32 + mt*16 + quad*4;
      #pragma unroll
      for (int r = 0; r < 4; ++r) {
        int el = ebase + r;
        float w = acc[r] + b2c;
        if (kind == 0) {
          atomicAdd(&outAcc[el][vv], w * sF[el][uu] * p0F[el]);
        } else if (kind == 1) {
          float base = w * sF[el][uu];
          atomicAdd(&outAcc[el][NS + vv*3 + 0], base * sh1nF[el][0]);
          atomicAdd(&outAcc[el][NS + vv*3 + 1], base * sh1nF[el][1]);
          atomicAdd(&outAcc[el][NS + vv*3 + 2], base * sh1nF[el][2]);
        } else if (kind == 2) {
          float base = w * q0F[el];
          atomicAdd(&outAcc[el][NS + vv*3 + 0], base * vF[el][uu*3+0]);
          atomicAdd(&outAcc[el][NS + vv*3 + 1], base * vF[el][uu*3+1]);
          atomicAdd(&outAcc[el][NS + vv*3 + 2], base * vF[el][uu*3+2]);
        } else {
          atomicAdd(&outAcc[el][vv], w * dotN[el][uu]);
        }
      }
    }
  }
  __syncthreads();

  for (int i = tid; i < 64 * NATT; i += 128) {
    int el = i / NATT, oi = i % NATT;
    int src = srcL[el];
    if (src >= 0) atomicAdd(&summed[(size_t)src * NATT + oi], outAcc[el][oi]);
  }
  if (tid < 64) {
    int src = srcL[tid];
    if (src >= 0) atomicAdd(&cnt[src], 1.0f);
  }
}

// ---------------- K4: mean over segment + residual, accumulate BN stats ---------
__global__ __launch_bounds__(256) void k_node(const float* __restrict__ summed,
                                              const float* __restrict__ cnt,
                                              const float* __restrict__ node_attr,
                                              float* __restrict__ outp,
                                              float* __restrict__ stats) {
  __shared__ float ls[NS], lq[NS], lv[NV];
  int tid = threadIdx.x;
  if (tid < NS) { ls[tid] = 0.f; lq[tid] = 0.f; }
  if (tid < NV) lv[tid] = 0.f;
  __syncthreads();
  int i = blockIdx.x * 256 + tid;
  if (i < NNODE * NATT) {
    int row = i / NATT, colc = i % NATT;
    float x = summed[i] / fmaxf(cnt[row], 1.f) + node_attr[i];
    outp[i] = x;
    if (colc < NS) { atomicAdd(&ls[colc], x); atomicAdd(&lq[colc], x * x); }
    else           { atomicAdd(&lv[(colc - NS) / 3], x * x); }
  }
  __syncthreads();
  if (tid < NS) { atomicAdd(&stats[tid], ls[tid]); atomicAdd(&stats[NS + tid], lq[tid]); }
  if (tid < NV) atomicAdd(&stats[96 + tid], lv[tid]);
}

// ---------------- K5: batch norm apply ------------------------------------------
__global__ __launch_bounds__(256) void k_bn(const float* __restrict__ outp,
                                            const float* __restrict__ stats,
                                            const float* __restrict__ bnw,
                                            const float* __restrict__ bnb,
                                            float* __restrict__ out) {
  int i = blockIdx.x * 256 + threadIdx.x;
  if (i >= NNODE * NATT) return;
  int colc = i % NATT;
  float x = outp[i];
  float r;
  if (colc < NS) {
    float mean = stats[colc] * (1.f / NNODE);
    float var  = stats[NS + colc] * (1.f / NNODE) - mean * mean;
    r = (x - mean) * rsqrtf(var + EPSV) * bnw[colc] + bnb[colc];
  } else {
    int u = (colc - NS) / 3;
    float vn = stats[96 + u] * (1.f / (3.f * NNODE));
    r = x * rsqrtf(vn + EPSV) * bnw[NS + u];
  }
  out[i] = r;
}

extern "C" void kernel_launch(void* const* d_in, const int* in_sizes, int n_in,
                              void* d_out, int out_size, void* d_ws, size_t ws_size,
                              hipStream_t stream) {
  const float* node_attr = (const float*)d_in[0];
  const int*   eidx      = (const int*)d_in[1];
  const float* edge_attr = (const float*)d_in[2];
  const float* esh       = (const float*)d_in[3];
  const float* fw1       = (const float*)d_in[4];
  const float* fb1       = (const float*)d_in[5];
  const float* fw2       = (const float*)d_in[6];
  const float* fb2       = (const float*)d_in[7];
  const float* bnw       = (const float*)d_in[8];
  const float* bnb       = (const float*)d_in[9];
  float* out = (float*)d_out;

  char* ws = (char*)d_ws;
  // layout (bytes):
  //   Bt     @ 0        : CPAD*128*2      =   864,256
  //   hbf    @ 864256   : EPAD*128*2      = 12,812,288
  //   summed @ 13676544 : N*78*4          =  3,120,000
  //   cnt    @ 16796544 : N*4             =     40,000
  //   stats  @ 16836544 : 128*4           =        512
  //   outp   @ 16837056 : N*78*4          =  3,120,000
  unsigned short* Bt     = (unsigned short*)(ws + 0);
  unsigned short* hbf    = (unsigned short*)(ws + 864256);
  float*          summed = (float*)(ws + 13676544);
  float*          cnt    = (float*)(ws + 16796544);
  float*          stats  = (float*)(ws + 16836544);
  float*          outp   = (float*)(ws + 16837056);

  hipMemsetAsync(ws + 13676544, 0, 3120000 + 40000 + 512, stream);

  k_prep_bt<<<(CPAD * 128) / 256, 256, 0, stream>>>(fw2, Bt);
  k_fc1<<<EPAD / 32, 256, 0, stream>>>(edge_attr, fw1, fb1, hbf);
  k_tp<<<EPAD / 64, 128, 0, stream>>>(hbf, Bt, fb2, eidx, node_attr, esh, summed, cnt);
  int nelem_blocks = (NNODE * NATT + 255) / 256;
  k_node<<<nelem_blocks, 256, 0, stream>>>(summed, cnt, node_attr, outp, stats);
  k_bn<<<nelem_blocks, 256, 0, stream>>>(outp, stats, bnw, bnb, out);
}

// Round 2
// 416.282 us; speedup vs baseline: 4.4381x; 4.4381x over previous
//
#include <hip/hip_runtime.h>
#include <hip/hip_bf16.h>

#define NS 48
#define NV 10
#define NATT 78
#define HID 128
#define W1N 2304
#define W2N 480
#define W3N 100
#define W4N 480
#define WTOT 3364
#define NEDGE 50000
#define NNODE 10000
#define EPAD 50048       // 1564 * 32
#define EPSV 1e-5f
#define INV_SQRT3 0.57735026918962576f
#define NORM0 0.13130643285972254f   // 1/sqrt(58)
#define NORM1 0.13130643285972254f

// Repacked Bt2 column layout (tiles of 16 cols, 232 tiles = 3712 cols):
//  A: tiles   0..143  w1  c'=u*48+v            (u=t/3, v=16*(t%3)+col)
//  B: tiles 144..173  w4  c'=2304+u*48+v
//  C: tiles 174..221  w2  one u per tile, col=v (v<10 valid, rest zero-pad)
//  D: tiles 222..231  w3  one u per tile, col=v (v<10 valid)
#define CPAD2 3712
#define NT_A 144
#define NT_B 30
#define NT_C 48
#define NT_D 10

using short8 = __attribute__((ext_vector_type(8))) short;
using f32x4  = __attribute__((ext_vector_type(4))) float;

__device__ __forceinline__ unsigned short f2bf(float x) {
  union { float f; unsigned u; } v; v.f = x;
  unsigned r = v.u + 0x7fff + ((v.u >> 16) & 1);
  return (unsigned short)(r >> 16);
}

// ---------------- K0: fc_w2 (128 x 3364) -> Bt2 bf16 [CPAD2][128] + b2p ---------
__global__ __launch_bounds__(256) void k_prep_bt2(const float* __restrict__ w2,
                                                  const float* __restrict__ b2,
                                                  unsigned short* __restrict__ Bt2,
                                                  float* __restrict__ b2p) {
  int idx = blockIdx.x * 256 + threadIdx.x;   // CPAD2*128 total
  int cp = idx >> 7, k = idx & 127;
  int c_src = -1;
  if (cp < 2304)      c_src = cp;                                   // w1
  else if (cp < 2784) c_src = 2884 + (cp - 2304);                   // w4
  else if (cp < 3552) { int t = cp - 2784; int u = t >> 4, v = t & 15;
                        if (v < 10) c_src = 2304 + u * 10 + v; }    // w2
  else                { int t = cp - 3552; int u = t >> 4, v = t & 15;
                        if (v < 10) c_src = 2784 + u * 10 + v; }    // w3
  Bt2[idx] = (c_src >= 0) ? f2bf(w2[(size_t)k * WTOT + c_src]) : (unsigned short)0;
  if (k == 0) b2p[cp] = (c_src >= 0) ? b2[c_src] : 0.f;
}

// ---------------- K1: h = relu(edge_attr @ fc_w1 + b1) -> bf16 [EPAD][128] ------
__global__ __launch_bounds__(256) void k_fc1(const float* __restrict__ ea,
                                             const float* __restrict__ w1,
                                             const float* __restrict__ b1,
                                             unsigned short* __restrict__ hbf) {
  __shared__ float sT[128][36];
  int tid = threadIdx.x;
  int e0 = blockIdx.x * 32;
  for (int i = tid; i < 32 * 128; i += 256) {
    int el = i >> 7, k = i & 127;
    int e = e0 + el;
    sT[k][el] = (e < NEDGE) ? ea[(size_t)e * 128 + k] : 0.f;
  }
  __syncthreads();
  int cg = tid & 31;
  int eg = tid >> 5;
  float acc[4][4] = {};
  #pragma unroll 4
  for (int k = 0; k < 128; ++k) {
    float4 a = *(const float4*)&sT[k][eg * 4];
    float4 w = *(const float4*)&w1[k * 128 + cg * 4];
    float av[4] = {a.x, a.y, a.z, a.w};
    float wv[4] = {w.x, w.y, w.z, w.w};
    #pragma unroll
    for (int ii = 0; ii < 4; ++ii)
      #pragma unroll
      for (int jj = 0; jj < 4; ++jj)
        acc[ii][jj] += av[ii] * wv[jj];
  }
  float bb[4];
  #pragma unroll
  for (int jj = 0; jj < 4; ++jj) bb[jj] = b1[cg * 4 + jj];
  #pragma unroll
  for (int ii = 0; ii < 4; ++ii) {
    int e = e0 + eg * 4 + ii;
    bool val = e < NEDGE;
    unsigned short h4[4];
    #pragma unroll
    for (int jj = 0; jj < 4; ++jj) {
      float r = val ? fmaxf(acc[ii][jj] + bb[jj], 0.f) : 0.f;
      h4[jj] = f2bf(r);
    }
    uint2 pk;
    pk.x = (unsigned)h4[0] | ((unsigned)h4[1] << 16);
    pk.y = (unsigned)h4[2] | ((unsigned)h4[3] << 16);
    *(uint2*)(hbf + (size_t)e * 128 + cg * 4) = pk;
  }
}

// ---------------- K3: fused GEMM + tensor product, register epilogue ------------
__global__ __launch_bounds__(64, 2) void k_tp(const unsigned short* __restrict__ hbf,
                                              const unsigned short* __restrict__ Bt2,
                                              const float* __restrict__ b2p,
                                              const int* __restrict__ eidx,
                                              const float* __restrict__ node_attr,
                                              const float* __restrict__ esh,
                                              float* __restrict__ summed,
                                              float* __restrict__ cnt) {
  __shared__ float sF[32][49];     // pad 49: stride*4 != 0 mod 32 banks
  __shared__ float vF[32][30];
  __shared__ float dotN[32][10];   // dot * INV_SQRT3 * NORM0
  __shared__ float p0F[32], q0F[32];
  __shared__ float sh1nF[32][3];
  __shared__ int   srcL[32], dstL[32];

  int tid = threadIdx.x;           // 64 threads = 1 wave
  int e0 = blockIdx.x * 32;

  float s1x = 0.f, s1y = 0.f, s1z = 0.f;
  if (tid < 32) {
    int eg = e0 + tid;
    bool val = eg < NEDGE;
    srcL[tid] = val ? eidx[eg] : -1;
    dstL[tid] = val ? eidx[NEDGE + eg] : -1;
    float sh0 = 0.f;
    if (val) {
      float4 s4 = *(const float4*)&esh[(size_t)eg * 4];
      sh0 = s4.x; s1x = s4.y; s1y = s4.z; s1z = s4.w;
    }
    p0F[tid] = sh0 * NORM0;
    q0F[tid] = sh0 * NORM1;
    sh1nF[tid][0] = s1x * NORM1; sh1nF[tid][1] = s1y * NORM1; sh1nF[tid][2] = s1z * NORM1;
  }
  __syncthreads();
  for (int i = tid; i < 32 * NATT; i += 64) {
    int el = i / NATT, a = i % NATT;
    int dst = dstL[el];
    float x = (dst >= 0) ? node_attr[(size_t)dst * NATT + a] : 0.f;
    if (a < NS) sF[el][a] = x; else vF[el][a - NS] = x;
  }
  __syncthreads();
  if (tid < 32) {
    #pragma unroll
    for (int u = 0; u < NV; ++u)
      dotN[tid][u] = (vF[tid][u*3] * s1x + vF[tid][u*3+1] * s1y + vF[tid][u*3+2] * s1z)
                     * (INV_SQRT3 * NORM0);
  }
  __syncthreads();

  int quad = tid >> 4;
  int col  = tid & 15;
  int elq  = quad * 4;             // el = mt*16 + elq + r

  // A fragments in registers: 32 edges x K=128
  short8 aF[2][4];
  {
    const short8* hp = (const short8*)hbf;
    #pragma unroll
    for (int mt = 0; mt < 2; ++mt) {
      size_t row = (size_t)(e0 + mt * 16 + col) * 16;
      #pragma unroll
      for (int ks = 0; ks < 4; ++ks) aF[mt][ks] = hp[row + ks * 4 + quad];
    }
  }
  float p0v[2][4];
  #pragma unroll
  for (int mt = 0; mt < 2; ++mt)
    #pragma unroll
    for (int r = 0; r < 4; ++r) p0v[mt][r] = p0F[mt * 16 + elq + r];

  const short8* bp = (const short8*)Bt2;

  float acc0[2][4][3] = {};   // out0[el][16j+col]
  float t1a[2][4]     = {};   // sum_u w2[u,col]*s[u]   (col<10)
  float t3a[2][4][3]  = {};   // sum_u w3[u,col]*v[u][i]

  auto do_tile = [&](int t, f32x4& m0, f32x4& m1) {
    const short8* bb = bp + (size_t)(t * 16 + col) * 16 + quad;
    short8 b0 = bb[0], b1_ = bb[4], b2_ = bb[8], b3 = bb[12];
    f32x4 a0 = {0.f,0.f,0.f,0.f}, a1 = {0.f,0.f,0.f,0.f};
    a0 = __builtin_amdgcn_mfma_f32_16x16x32_bf16(aF[0][0], b0,  a0, 0, 0, 0);
    a0 = __builtin_amdgcn_mfma_f32_16x16x32_bf16(aF[0][1], b1_, a0, 0, 0, 0);
    a0 = __builtin_amdgcn_mfma_f32_16x16x32_bf16(aF[0][2], b2_, a0, 0, 0, 0);
    a0 = __builtin_amdgcn_mfma_f32_16x16x32_bf16(aF[0][3], b3,  a0, 0, 0, 0);
    a1 = __builtin_amdgcn_mfma_f32_16x16x32_bf16(aF[1][0], b0,  a1, 0, 0, 0);
    a1 = __builtin_amdgcn_mfma_f32_16x16x32_bf16(aF[1][1], b1_, a1, 0, 0, 0);
    a1 = __builtin_amdgcn_mfma_f32_16x16x32_bf16(aF[1][2], b2_, a1, 0, 0, 0);
    a1 = __builtin_amdgcn_mfma_f32_16x16x32_bf16(aF[1][3], b3,  a1, 0, 0, 0);
    m0 = a0; m1 = a1;
  };

  // ---- Region A: w1, 48 u-groups x 3 tiles ----
  #pragma unroll 1
  for (int u = 0; u < 48; ++u) {
    float sfac[2][4];
    #pragma unroll
    for (int mt = 0; mt < 2; ++mt)
      #pragma unroll
      for (int r = 0; r < 4; ++r)
        sfac[mt][r] = sF[mt * 16 + elq + r][u] * p0v[mt][r];
    #pragma unroll
    for (int j = 0; j < 3; ++j) {
      int t = u * 3 + j;
      float b2c = b2p[t * 16 + col];
      f32x4 m0, m1;
      do_tile(t, m0, m1);
      #pragma unroll
      for (int r = 0; r < 4; ++r) {
        acc0[0][r][j] += (m0[r] + b2c) * sfac[0][r];
        acc0[1][r][j] += (m1[r] + b2c) * sfac[1][r];
      }
    }
  }
  // ---- Region B: w4, 10 u-groups x 3 tiles ----
  #pragma unroll 1
  for (int u = 0; u < 10; ++u) {
    float dfac[2][4];
    #pragma unroll
    for (int mt = 0; mt < 2; ++mt)
      #pragma unroll
      for (int r = 0; r < 4; ++r)
        dfac[mt][r] = dotN[mt * 16 + elq + r][u];
    #pragma unroll
    for (int j = 0; j < 3; ++j) {
      int t = NT_A + u * 3 + j;
      float b2c = b2p[t * 16 + col];
      f32x4 m0, m1;
      do_tile(t, m0, m1);
      #pragma unroll
      for (int r = 0; r < 4; ++r) {
        acc0[0][r][j] += (m0[r] + b2c) * dfac[0][r];
        acc0[1][r][j] += (m1[r] + b2c) * dfac[1][r];
      }
    }
  }
  // ---- Region C: w2, 48 tiles (one u each), col = v ----
  #pragma unroll 2
  for (int u = 0; u < 48; ++u) {
    int t = NT_A + NT_B + u;
    float b2c = b2p[t * 16 + col];
    float sc[2][4];
    #pragma unroll
    for (int mt = 0; mt < 2; ++mt)
      #pragma unroll
      for (int r = 0; r < 4; ++r)
        sc[mt][r] = sF[mt * 16 + elq + r][u];
    f32x4 m0, m1;
    do_tile(t, m0, m1);
    #pragma unroll
    for (int r = 0; r < 4; ++r) {
      t1a[0][r] += (m0[r] + b2c) * sc[0][r];
      t1a[1][r] += (m1[r] + b2c) * sc[1][r];
    }
  }
  // ---- Region D: w3, 10 tiles (one u each), col = v ----
  #pragma unroll 1
  for (int u = 0; u < 10; ++u) {
    int t = NT_A + NT_B + NT_C + u;
    float b2c = b2p[t * 16 + col];
    f32x4 m0, m1;
    do_tile(t, m0, m1);
    #pragma unroll
    for (int mt = 0; mt < 2; ++mt)
      #pragma unroll
      for (int r = 0; r < 4; ++r) {
        float w = (mt == 0 ? m0[r] : m1[r]) + b2c;
        int el = mt * 16 + elq + r;
        #pragma unroll
        for (int i = 0; i < 3; ++i)
          t3a[mt][r][i] += w * vF[el][u * 3 + i];
      }
  }

  // ---- Flush: registers -> global atomics ----
  #pragma unroll
  for (int mt = 0; mt < 2; ++mt)
    #pragma unroll
    for (int r = 0; r < 4; ++r) {
      int el = mt * 16 + elq + r;
      int src = srcL[el];
      if (src < 0) continue;
      float* dp = &summed[(size_t)src * NATT];
      #pragma unroll
      for (int j = 0; j < 3; ++j)
        atomicAdd(dp + j * 16 + col, acc0[mt][r][j]);
      if (col < 10) {
        float q0 = q0F[el];
        #pragma unroll
        for (int i = 0; i < 3; ++i)
          atomicAdd(dp + NS + col * 3 + i,
                    t1a[mt][r] * sh1nF[el][i] + t3a[mt][r][i] * q0);
      }
    }
  if (tid < 32 && srcL[tid] >= 0) atomicAdd(&cnt[srcL[tid]], 1.0f);
}

// ---------------- K4: mean over segment + residual, accumulate BN stats ---------
__global__ __launch_bounds__(256) void k_node(const float* __restrict__ summed,
                                              const float* __restrict__ cnt,
                                              const float* __restrict__ node_attr,
                                              float* __restrict__ outp,
                                              float* __restrict__ stats) {
  __shared__ float ls[NS], lq[NS], lv[NV];
  int tid = threadIdx.x;
  if (tid < NS) { ls[tid] = 0.f; lq[tid] = 0.f; }
  if (tid < NV) lv[tid] = 0.f;
  __syncthreads();
  int i = blockIdx.x * 256 + tid;
  if (i < NNODE * NATT) {
    int row = i / NATT, colc = i % NATT;
    float x = summed[i] / fmaxf(cnt[row], 1.f) + node_attr[i];
    outp[i] = x;
    if (colc < NS) { atomicAdd(&ls[colc], x); atomicAdd(&lq[colc], x * x); }
    else           { atomicAdd(&lv[(colc - NS) / 3], x * x); }
  }
  __syncthreads();
  if (tid < NS) { atomicAdd(&stats[tid], ls[tid]); atomicAdd(&stats[NS + tid], lq[tid]); }
  if (tid < NV) atomicAdd(&stats[96 + tid], lv[tid]);
}

// ---------------- K5: batch norm apply ------------------------------------------
__global__ __launch_bounds__(256) void k_bn(const float* __restrict__ outp,
                                            const float* __restrict__ stats,
                                            const float* __restrict__ bnw,
                                            const float* __restrict__ bnb,
                                            float* __restrict__ out) {
  int i = blockIdx.x * 256 + threadIdx.x;
  if (i >= NNODE * NATT) return;
  int colc = i % NATT;
  float x = outp[i];
  float r;
  if (colc < NS) {
    float mean = stats[colc] * (1.f / NNODE);
    float var  = stats[NS + colc] * (1.f / NNODE) - mean * mean;
    r = (x - mean) * rsqrtf(var + EPSV) * bnw[colc] + bnb[colc];
  } else {
    int u = (colc - NS) / 3;
    float vn = stats[96 + u] * (1.f / (3.f * NNODE));
    r = x * rsqrtf(vn + EPSV) * bnw[NS + u];
  }
  out[i] = r;
}

extern "C" void kernel_launch(void* const* d_in, const int* in_sizes, int n_in,
                              void* d_out, int out_size, void* d_ws, size_t ws_size,
                              hipStream_t stream) {
  const float* node_attr = (const float*)d_in[0];
  const int*   eidx      = (const int*)d_in[1];
  const float* edge_attr = (const float*)d_in[2];
  const float* esh       = (const float*)d_in[3];
  const float* fw1       = (const float*)d_in[4];
  const float* fb1       = (const float*)d_in[5];
  const float* fw2       = (const float*)d_in[6];
  const float* fb2       = (const float*)d_in[7];
  const float* bnw       = (const float*)d_in[8];
  const float* bnb       = (const float*)d_in[9];
  float* out = (float*)d_out;

  char* ws = (char*)d_ws;
  // layout (bytes):
  //   Bt2    @ 0        : CPAD2*128*2 =    950,272
  //   b2p    @ 950272   : CPAD2*4     =     14,848
  //   hbf    @ 965120   : EPAD*128*2  = 12,812,288
  //   summed @ 13777408 : N*78*4      =  3,120,000
  //   cnt    @ 16897408 : N*4         =     40,000
  //   stats  @ 16937408 : 128*4       =        512
  //   outp   @ 16937920 : N*78*4      =  3,120,000   (end 20,057,920)
  unsigned short* Bt2    = (unsigned short*)(ws + 0);
  float*          b2p    = (float*)(ws + 950272);
  unsigned short* hbf    = (unsigned short*)(ws + 965120);
  float*          summed = (float*)(ws + 13777408);
  float*          cnt    = (float*)(ws + 16897408);
  float*          stats  = (float*)(ws + 16937408);
  float*          outp   = (float*)(ws + 16937920);

  hipMemsetAsync(ws + 13777408, 0, 3120000 + 40000 + 512, stream);

  k_prep_bt2<<<(CPAD2 * 128) / 256, 256, 0, stream>>>(fw2, fb2, Bt2, b2p);
  k_fc1<<<EPAD / 32, 256, 0, stream>>>(edge_attr, fw1, fb1, hbf);
  k_tp<<<EPAD / 32, 64, 0, stream>>>(hbf, Bt2, b2p, eidx, node_attr, esh, summed, cnt);
  int nelem_blocks = (NNODE * NATT + 255) / 256;
  k_node<<<nelem_blocks, 256, 0, stream>>>(summed, cnt, node_attr, outp, stats);
  k_bn<<<nelem_blocks, 256, 0, stream>>>(outp, stats, bnw, bnb, out);
}